// Round 8
// baseline (331.172 us; speedup 1.0000x reference)
//
#include <hip/hip_runtime.h>

// NGP multiresolution hash-grid interpolation encoding.
// B=262144 points, DIM=3, L=16 levels, T=19 (2^19 entries/level), F=2.
//
// Structure: spatial counting-sort (points -> 16^3 buckets) -> level-phased
// gather with each level's table replicated in all 8 XCD L2s
// (cheap/expensive interleave {0,15,1,14,...} so the ~2-level dispatch
// window holds 1 expensive 4MiB table + 1 L1-resident cheap level) ->
// LDS transpose + un-permute (one full 128B out line per point).
//
// R8 changes vs R7:
//  - REVERT vf4 pair-loads (R7 regression: 66->86us; always-16B loads cost
//    more than the MSHR merge saved). Back to 8 plain vf2 gathers.
//  - Fuse hist+scan+scatter into ONE kernel with a manual grid barrier
//    (1024 blocks co-resident by capacity: 17KB LDS -> 9 blocks/CU, need 4;
//    device-scope atomics + threadfence). Pipeline = 4 dispatches
//    (memset, sort, gather, transpose) vs 6 in R6.

#define NB 262144
#define NL 16
#define TSIZE (1u << 19)
#define TMASK ((1u << 19) - 1u)
#define P1 2654435761u
#define P2 805459861u
#define NBKT 4096         // 16^3 spatial buckets
#define SORT_BLOCKS 1024  // NB / 256

typedef float vf2 __attribute__((ext_vector_type(2)));
typedef float vf4 __attribute__((ext_vector_type(4)));

__constant__ float RES_C[NL] = {16.f, 20.f, 25.f, 32.f, 40.f, 50.f, 64.f, 80.f,
                                101.f, 128.f, 161.f, 203.f, 256.f, 322.f, 406.f, 512.f};

// cheap/expensive interleave for the ~2-level dispatch window
__constant__ int SEQ_C[NL] = {0, 15, 1, 14, 2, 13, 3, 12, 4, 11, 5, 10, 6, 9, 7, 8};

__device__ __forceinline__ int bucket_of(float px, float py, float pz) {
  int bx = min(15, (int)(px * 16.0f));
  int by = min(15, (int)(py * 16.0f));
  int bz = min(15, (int)(pz * 16.0f));
  return bx | (by << 4) | (bz << 8);
}

__device__ __forceinline__ void ngp_point_level(
    float px, float py, float pz, int l, const float* __restrict__ tables,
    float& o0, float& o1) {
  const float res = RES_C[l];
  const float sx = px * res, sy = py * res, sz = pz * res;
  const float fx = floorf(sx), fy = floorf(sy), fz = floorf(sz);
  const unsigned ix = (unsigned)fx, iy = (unsigned)fy, iz = (unsigned)fz;

  const unsigned hx0 = ix, hx1 = ix + 1u;
  const unsigned hy0 = iy * P1, hy1 = hy0 + P1;
  const unsigned hz0 = iz * P2, hz1 = hz0 + P2;

  const float wx0 = 1.0f - fabsf(sx - fx);
  const float wx1 = 1.0f - fabsf(sx - (fx + 1.0f));
  const float wy0 = 1.0f - fabsf(sy - fy);
  const float wy1 = 1.0f - fabsf(sy - (fy + 1.0f));
  const float wz0 = 1.0f - fabsf(sz - fz);
  const float wz1 = 1.0f - fabsf(sz - (fz + 1.0f));

  const vf2* __restrict__ tbl = (const vf2*)tables + (size_t)l * TSIZE;

  unsigned idxs[8];
#pragma unroll
  for (int v = 0; v < 8; ++v) {
    const unsigned hx = (v & 1) ? hx1 : hx0;
    const unsigned hy = (v & 2) ? hy1 : hy0;
    const unsigned hz = (v & 4) ? hz1 : hz0;
    idxs[v] = (hx ^ hy ^ hz) & TMASK;
  }
  vf2 g[8];
#pragma unroll
  for (int v = 0; v < 8; ++v) g[v] = tbl[idxs[v]];

  o0 = 0.0f; o1 = 0.0f;
#pragma unroll
  for (int v = 0; v < 8; ++v) {
    const float w = ((v & 1) ? wx1 : wx0) * ((v & 2) ? wy1 : wy0) * ((v & 4) ? wz1 : wz0);
    o0 = fmaf(w, g[v].x, o0);
    o1 = fmaf(w, g[v].y, o1);
  }
}

// ---- fused sort: hist -> grid barrier -> redundant LDS scan -> scatter ----
__global__ __launch_bounds__(256) void sort_kernel(
    const float* __restrict__ x, unsigned* __restrict__ hist,
    unsigned* __restrict__ cnt, unsigned* __restrict__ bar,
    vf4* __restrict__ xp) {
  __shared__ unsigned soff[NBKT];
  __shared__ unsigned part[256];
  const int t = threadIdx.x;
  const int b = blockIdx.x * 256 + t;

  const float px = x[b * 3 + 0], py = x[b * 3 + 1], pz = x[b * 3 + 2];
  const int bkt = bucket_of(px, py, pz);
  atomicAdd(&hist[bkt], 1u);  // device-scope (L2 atomic)

  // ---- manual grid barrier (all 1024 blocks co-resident: 17KB LDS ->
  // 9 blocks/CU possible, 4 needed; graph replay runs this kernel alone) ----
  __syncthreads();
  if (t == 0) {
    __threadfence();
    atomicAdd(&bar[0], 1u);
    while (__hip_atomic_load(&bar[0], __ATOMIC_RELAXED,
                             __HIP_MEMORY_SCOPE_AGENT) < SORT_BLOCKS) {
      __builtin_amdgcn_s_sleep(2);
    }
  }
  __syncthreads();
  __threadfence();

  // redundant per-block exclusive scan of the 4096-entry histogram
  const int base = t * (NBKT / 256);  // 16 buckets per thread
  unsigned loc[NBKT / 256];
  unsigned s = 0;
#pragma unroll
  for (int i = 0; i < NBKT / 256; ++i) {
    loc[i] = s;
    s += __hip_atomic_load(&hist[base + i], __ATOMIC_RELAXED,
                           __HIP_MEMORY_SCOPE_AGENT);  // bypass L1
  }
  part[t] = s;
  __syncthreads();
  for (int d = 1; d < 256; d <<= 1) {
    unsigned v = (t >= d) ? part[t - d] : 0u;
    __syncthreads();
    part[t] += v;
    __syncthreads();
  }
  const unsigned pre = (t == 0) ? 0u : part[t - 1];
#pragma unroll
  for (int i = 0; i < NBKT / 256; ++i) soff[base + i] = pre + loc[i];
  __syncthreads();

  // scatter
  const unsigned rank = atomicAdd(&cnt[bkt], 1u);
  const unsigned pos = soff[bkt] + rank;
  vf4 v; v.x = px; v.y = py; v.z = pz; v.w = __uint_as_float((unsigned)b);
  xp[pos] = v;
}

// ---- phase 1: level-phased gather over sorted points ----
__global__ __launch_bounds__(256) void ngp_gather_sorted_kernel(
    const vf4* __restrict__ xp,        // (B,) sorted: x,y,z,orig_id
    const float* __restrict__ tables,  // (L, 2^19, 2)
    vf2* __restrict__ ws) {            // (L, B) in sorted order
  const int i = blockIdx.x;        // 0..16383
  const int lvl = SEQ_C[i >> 10];  // level-major phases
  const int chunk = i & 1023;
  const int p = chunk * 256 + threadIdx.x;

  const vf4 v = __builtin_nontemporal_load(xp + p);

  float o0, o1;
  ngp_point_level(v.x, v.y, v.z, lvl, tables, o0, o1);

  vf2 r; r.x = o0; r.y = o1;
  __builtin_nontemporal_store(r, ws + (size_t)lvl * NB + p);
}

// ---- phase 2: transpose + un-permute. Each point's out row = one 128B line. ----
__global__ __launch_bounds__(256) void ngp_transpose_sorted_kernel(
    const vf2* __restrict__ ws,   // (L, B) sorted order
    const vf4* __restrict__ xp,   // orig_id in .w
    vf4* __restrict__ out4) {     // (B, 8) float4 rows, original order
  __shared__ vf2 tile[NL][257];
  __shared__ unsigned pid[256];
  const int t = threadIdx.x;
  const int p0 = blockIdx.x * 256;

#pragma unroll
  for (int l = 0; l < NL; ++l) {
    tile[l][t] = __builtin_nontemporal_load(ws + (size_t)l * NB + p0 + t);
  }
  pid[t] = __float_as_uint(xp[p0 + t].w);
  __syncthreads();

#pragma unroll
  for (int k = 0; k < 8; ++k) {
    const int q = k * 256 + t;
    const int pq = q >> 3;
    const int wq = q & 7;
    const vf2 a = tile[2 * wq + 0][pq];
    const vf2 c = tile[2 * wq + 1][pq];
    vf4 v; v.x = a.x; v.y = a.y; v.z = c.x; v.w = c.y;
    out4[(size_t)pid[pq] * 8 + wq] = v;
  }
}

// ---- R3 path (no sort) if ws is small ----
__global__ __launch_bounds__(256) void ngp_gather_kernel(
    const float* __restrict__ x, const float* __restrict__ tables,
    vf2* __restrict__ ws) {
  const int i = blockIdx.x;
  const int lvl = (i & 7) | ((i >> 13) << 3);
  const int chunk = (i >> 3) & 1023;
  const int b = chunk * 256 + threadIdx.x;
  const float px = __builtin_nontemporal_load(x + b * 3 + 0);
  const float py = __builtin_nontemporal_load(x + b * 3 + 1);
  const float pz = __builtin_nontemporal_load(x + b * 3 + 2);
  float o0, o1;
  ngp_point_level(px, py, pz, lvl, tables, o0, o1);
  vf2 r; r.x = o0; r.y = o1;
  __builtin_nontemporal_store(r, ws + (size_t)lvl * NB + b);
}

__global__ __launch_bounds__(256) void ngp_transpose_kernel(
    const vf2* __restrict__ ws, vf4* __restrict__ out4) {
  __shared__ vf2 tile[NL][257];
  const int t = threadIdx.x;
  const int p0 = blockIdx.x * 256;
#pragma unroll
  for (int l = 0; l < NL; ++l) {
    tile[l][t] = __builtin_nontemporal_load(ws + (size_t)l * NB + p0 + t);
  }
  __syncthreads();
#pragma unroll
  for (int k = 0; k < 8; ++k) {
    const int q = k * 256 + t;
    const int pq = q >> 3;
    const int wq = q & 7;
    const vf2 a = tile[2 * wq + 0][pq];
    const vf2 c = tile[2 * wq + 1][pq];
    vf4 v; v.x = a.x; v.y = a.y; v.z = c.x; v.w = c.y;
    __builtin_nontemporal_store(v, out4 + (size_t)p0 * 8 + q);
  }
}

// ---- last-resort fused fallback ----
__global__ __launch_bounds__(256) void ngp_fused_kernel(
    const float* __restrict__ x, const float* __restrict__ tables,
    float* __restrict__ out) {
  const int tid = blockIdx.x * blockDim.x + threadIdx.x;
  const int l = tid & (NL - 1);
  const int b = tid >> 4;
  float o0, o1;
  ngp_point_level(x[b * 3], x[b * 3 + 1], x[b * 3 + 2], l, tables, o0, o1);
  float2 r = make_float2(o0, o1);
  ((float2*)out)[tid] = r;
}

extern "C" void kernel_launch(void* const* d_in, const int* in_sizes, int n_in,
                              void* d_out, int out_size, void* d_ws, size_t ws_size,
                              hipStream_t stream) {
  const float* x = (const float*)d_in[0];
  const float* tables = (const float*)d_in[1];
  float* out = (float*)d_out;

  const size_t ws2_b = (size_t)NL * NB * sizeof(vf2);     // 32 MB
  const size_t xp_b = (size_t)NB * sizeof(vf4);           // 4 MB
  const size_t hist_b = (size_t)NBKT * sizeof(unsigned);  // 16 KB
  const size_t bar_b = 256;                               // barrier counter
  const size_t sorted_need = ws2_b + xp_b + 2 * hist_b + bar_b;

  if (ws_size >= sorted_need) {
    char* base = (char*)d_ws;
    vf2* ws2 = (vf2*)base;
    vf4* xp = (vf4*)(base + ws2_b);
    unsigned* hist = (unsigned*)(base + ws2_b + xp_b);
    unsigned* cnt = (unsigned*)(base + ws2_b + xp_b + hist_b);
    unsigned* bar = (unsigned*)(base + ws2_b + xp_b + 2 * hist_b);

    hipMemsetAsync(hist, 0, 2 * hist_b + bar_b, stream);  // hist + cnt + bar
    sort_kernel<<<SORT_BLOCKS, 256, 0, stream>>>(x, hist, cnt, bar, xp);
    ngp_gather_sorted_kernel<<<NB * NL / 256, 256, 0, stream>>>(xp, tables, ws2);
    ngp_transpose_sorted_kernel<<<NB / 256, 256, 0, stream>>>(ws2, xp, (vf4*)out);
  } else if (ws_size >= ws2_b) {
    vf2* ws = (vf2*)d_ws;
    ngp_gather_kernel<<<NB * NL / 256, 256, 0, stream>>>(x, tables, ws);
    ngp_transpose_kernel<<<NB / 256, 256, 0, stream>>>(ws, (vf4*)out);
  } else {
    ngp_fused_kernel<<<NB * NL / 256, 256, 0, stream>>>(x, tables, out);
  }
}

// Round 9
// 216.088 us; speedup vs baseline: 1.5326x; 1.5326x over previous
//
#include <hip/hip_runtime.h>

// NGP multiresolution hash-grid interpolation encoding.
// B=262144 points, DIM=3, L=16 levels, T=19 (2^19 entries/level), F=2.
//
// R9 = R6 gather (proven 66us) + R7's lean split sort. R8's single-kernel
// grid-barrier sort was 165us (spin + device-scope polling serialization) —
// reverted to split dispatches.
// Pipeline (5 dispatches):
//   memset(32KB+)  -> hist (262K bucket atomics)
//   scatter        -> fused redundant per-block LDS scan of the 4096-entry
//                     histogram + ticketed scatter to xp (x,y,z,orig_id)
//   gather         -> level-phased, table replicated in all 8 XCD L2s;
//                     cheap/expensive interleave {0,15,1,14,...} so the
//                     ~2-level dispatch window = 1 expensive table (L2) +
//                     1 cheap level (L1 via spatial sort). 8 plain vf2
//                     gathers/point (R7's vf4 pairing regressed: 66->86us).
//   transpose      -> LDS transpose + un-permute; one full 128B line/point.
// Floor model: 9 hash-saturated levels x 2.1M random 8B requests at
// 16 req/cyc/L2 x 8 L2s ~= 63us — gather is at that floor.

#define NB 262144
#define NL 16
#define TSIZE (1u << 19)
#define TMASK ((1u << 19) - 1u)
#define P1 2654435761u
#define P2 805459861u
#define NBKT 4096  // 16^3 spatial buckets: 64 pts/bucket ~ 1 wave/bucket

typedef float vf2 __attribute__((ext_vector_type(2)));
typedef float vf4 __attribute__((ext_vector_type(4)));

__constant__ float RES_C[NL] = {16.f, 20.f, 25.f, 32.f, 40.f, 50.f, 64.f, 80.f,
                                101.f, 128.f, 161.f, 203.f, 256.f, 322.f, 406.f, 512.f};

__constant__ int SEQ_C[NL] = {0, 15, 1, 14, 2, 13, 3, 12, 4, 11, 5, 10, 6, 9, 7, 8};

__device__ __forceinline__ int bucket_of(float px, float py, float pz) {
  int bx = min(15, (int)(px * 16.0f));
  int by = min(15, (int)(py * 16.0f));
  int bz = min(15, (int)(pz * 16.0f));
  return bx | (by << 4) | (bz << 8);
}

__device__ __forceinline__ void ngp_point_level(
    float px, float py, float pz, int l, const float* __restrict__ tables,
    float& o0, float& o1) {
  const float res = RES_C[l];
  const float sx = px * res, sy = py * res, sz = pz * res;
  const float fx = floorf(sx), fy = floorf(sy), fz = floorf(sz);
  const unsigned ix = (unsigned)fx, iy = (unsigned)fy, iz = (unsigned)fz;

  const unsigned hx0 = ix, hx1 = ix + 1u;
  const unsigned hy0 = iy * P1, hy1 = hy0 + P1;
  const unsigned hz0 = iz * P2, hz1 = hz0 + P2;

  const float wx0 = 1.0f - fabsf(sx - fx);
  const float wx1 = 1.0f - fabsf(sx - (fx + 1.0f));
  const float wy0 = 1.0f - fabsf(sy - fy);
  const float wy1 = 1.0f - fabsf(sy - (fy + 1.0f));
  const float wz0 = 1.0f - fabsf(sz - fz);
  const float wz1 = 1.0f - fabsf(sz - (fz + 1.0f));

  const vf2* __restrict__ tbl = (const vf2*)tables + (size_t)l * TSIZE;

  unsigned idxs[8];
#pragma unroll
  for (int v = 0; v < 8; ++v) {
    const unsigned hx = (v & 1) ? hx1 : hx0;
    const unsigned hy = (v & 2) ? hy1 : hy0;
    const unsigned hz = (v & 4) ? hz1 : hz0;
    idxs[v] = (hx ^ hy ^ hz) & TMASK;
  }
  vf2 g[8];
#pragma unroll
  for (int v = 0; v < 8; ++v) g[v] = tbl[idxs[v]];

  o0 = 0.0f; o1 = 0.0f;
#pragma unroll
  for (int v = 0; v < 8; ++v) {
    const float w = ((v & 1) ? wx1 : wx0) * ((v & 2) ? wy1 : wy0) * ((v & 4) ? wz1 : wz0);
    o0 = fmaf(w, g[v].x, o0);
    o1 = fmaf(w, g[v].y, o1);
  }
}

// ---- sort phase (split kernels; R8 fusion regressed badly) ----
__global__ __launch_bounds__(256) void hist_kernel(
    const float* __restrict__ x, unsigned* __restrict__ hist) {
  const int b = blockIdx.x * 256 + threadIdx.x;
  const float px = x[b * 3 + 0], py = x[b * 3 + 1], pz = x[b * 3 + 2];
  atomicAdd(&hist[bucket_of(px, py, pz)], 1u);
}

// scatter with fused (redundant per-block) exclusive scan of the histogram
__global__ __launch_bounds__(256) void scatter_kernel(
    const float* __restrict__ x, const unsigned* __restrict__ hist,
    unsigned* __restrict__ cnt, vf4* __restrict__ xp) {
  __shared__ unsigned soff[NBKT];
  __shared__ unsigned part[256];
  const int t = threadIdx.x;
  const int base = t * (NBKT / 256);  // 16 buckets per thread

  unsigned loc[NBKT / 256];
  unsigned s = 0;
#pragma unroll
  for (int i = 0; i < NBKT / 256; ++i) { loc[i] = s; s += hist[base + i]; }
  part[t] = s;
  __syncthreads();
  for (int d = 1; d < 256; d <<= 1) {
    unsigned v = (t >= d) ? part[t - d] : 0u;
    __syncthreads();
    part[t] += v;
    __syncthreads();
  }
  const unsigned pre = (t == 0) ? 0u : part[t - 1];
#pragma unroll
  for (int i = 0; i < NBKT / 256; ++i) soff[base + i] = pre + loc[i];
  __syncthreads();

  const int b = blockIdx.x * 256 + t;
  const float px = x[b * 3 + 0], py = x[b * 3 + 1], pz = x[b * 3 + 2];
  const int bkt = bucket_of(px, py, pz);
  const unsigned rank = atomicAdd(&cnt[bkt], 1u);
  const unsigned pos = soff[bkt] + rank;
  vf4 v; v.x = px; v.y = py; v.z = pz; v.w = __uint_as_float((unsigned)b);
  xp[pos] = v;
}

// ---- phase 1: level-phased gather over sorted points ----
__global__ __launch_bounds__(256) void ngp_gather_sorted_kernel(
    const vf4* __restrict__ xp,        // (B,) sorted: x,y,z,orig_id
    const float* __restrict__ tables,  // (L, 2^19, 2)
    vf2* __restrict__ ws) {            // (L, B) in sorted order
  const int i = blockIdx.x;        // 0..16383
  const int lvl = SEQ_C[i >> 10];  // level-major phases
  const int chunk = i & 1023;
  const int p = chunk * 256 + threadIdx.x;

  const vf4 v = __builtin_nontemporal_load(xp + p);

  float o0, o1;
  ngp_point_level(v.x, v.y, v.z, lvl, tables, o0, o1);

  vf2 r; r.x = o0; r.y = o1;
  __builtin_nontemporal_store(r, ws + (size_t)lvl * NB + p);
}

// ---- phase 2: transpose + un-permute. Each point's out row = one 128B line. ----
__global__ __launch_bounds__(256) void ngp_transpose_sorted_kernel(
    const vf2* __restrict__ ws,   // (L, B) sorted order
    const vf4* __restrict__ xp,   // orig_id in .w
    vf4* __restrict__ out4) {     // (B, 8) float4 rows, original order
  __shared__ vf2 tile[NL][257];
  __shared__ unsigned pid[256];
  const int t = threadIdx.x;
  const int p0 = blockIdx.x * 256;

#pragma unroll
  for (int l = 0; l < NL; ++l) {
    tile[l][t] = __builtin_nontemporal_load(ws + (size_t)l * NB + p0 + t);
  }
  pid[t] = __float_as_uint(xp[p0 + t].w);
  __syncthreads();

#pragma unroll
  for (int k = 0; k < 8; ++k) {
    const int q = k * 256 + t;
    const int pq = q >> 3;
    const int wq = q & 7;
    const vf2 a = tile[2 * wq + 0][pq];
    const vf2 c = tile[2 * wq + 1][pq];
    vf4 v; v.x = a.x; v.y = a.y; v.z = c.x; v.w = c.y;
    out4[(size_t)pid[pq] * 8 + wq] = v;
  }
}

// ---- R3 path (no sort) if ws is small ----
__global__ __launch_bounds__(256) void ngp_gather_kernel(
    const float* __restrict__ x, const float* __restrict__ tables,
    vf2* __restrict__ ws) {
  const int i = blockIdx.x;
  const int lvl = (i & 7) | ((i >> 13) << 3);
  const int chunk = (i >> 3) & 1023;
  const int b = chunk * 256 + threadIdx.x;
  const float px = __builtin_nontemporal_load(x + b * 3 + 0);
  const float py = __builtin_nontemporal_load(x + b * 3 + 1);
  const float pz = __builtin_nontemporal_load(x + b * 3 + 2);
  float o0, o1;
  ngp_point_level(px, py, pz, lvl, tables, o0, o1);
  vf2 r; r.x = o0; r.y = o1;
  __builtin_nontemporal_store(r, ws + (size_t)lvl * NB + b);
}

__global__ __launch_bounds__(256) void ngp_transpose_kernel(
    const vf2* __restrict__ ws, vf4* __restrict__ out4) {
  __shared__ vf2 tile[NL][257];
  const int t = threadIdx.x;
  const int p0 = blockIdx.x * 256;
#pragma unroll
  for (int l = 0; l < NL; ++l) {
    tile[l][t] = __builtin_nontemporal_load(ws + (size_t)l * NB + p0 + t);
  }
  __syncthreads();
#pragma unroll
  for (int k = 0; k < 8; ++k) {
    const int q = k * 256 + t;
    const int pq = q >> 3;
    const int wq = q & 7;
    const vf2 a = tile[2 * wq + 0][pq];
    const vf2 c = tile[2 * wq + 1][pq];
    vf4 v; v.x = a.x; v.y = a.y; v.z = c.x; v.w = c.y;
    __builtin_nontemporal_store(v, out4 + (size_t)p0 * 8 + q);
  }
}

// ---- last-resort fused fallback ----
__global__ __launch_bounds__(256) void ngp_fused_kernel(
    const float* __restrict__ x, const float* __restrict__ tables,
    float* __restrict__ out) {
  const int tid = blockIdx.x * blockDim.x + threadIdx.x;
  const int l = tid & (NL - 1);
  const int b = tid >> 4;
  float o0, o1;
  ngp_point_level(x[b * 3], x[b * 3 + 1], x[b * 3 + 2], l, tables, o0, o1);
  float2 r = make_float2(o0, o1);
  ((float2*)out)[tid] = r;
}

extern "C" void kernel_launch(void* const* d_in, const int* in_sizes, int n_in,
                              void* d_out, int out_size, void* d_ws, size_t ws_size,
                              hipStream_t stream) {
  const float* x = (const float*)d_in[0];
  const float* tables = (const float*)d_in[1];
  float* out = (float*)d_out;

  const size_t ws2_b = (size_t)NL * NB * sizeof(vf2);     // 32 MB
  const size_t xp_b = (size_t)NB * sizeof(vf4);           // 4 MB
  const size_t hist_b = (size_t)NBKT * sizeof(unsigned);  // 16 KB
  const size_t sorted_need = ws2_b + xp_b + 2 * hist_b;

  if (ws_size >= sorted_need) {
    char* base = (char*)d_ws;
    vf2* ws2 = (vf2*)base;
    vf4* xp = (vf4*)(base + ws2_b);
    unsigned* hist = (unsigned*)(base + ws2_b + xp_b);
    unsigned* cnt = (unsigned*)(base + ws2_b + xp_b + hist_b);

    hipMemsetAsync(hist, 0, 2 * hist_b, stream);  // hist + cnt
    hist_kernel<<<NB / 256, 256, 0, stream>>>(x, hist);
    scatter_kernel<<<NB / 256, 256, 0, stream>>>(x, hist, cnt, xp);
    ngp_gather_sorted_kernel<<<NB * NL / 256, 256, 0, stream>>>(xp, tables, ws2);
    ngp_transpose_sorted_kernel<<<NB / 256, 256, 0, stream>>>(ws2, xp, (vf4*)out);
  } else if (ws_size >= ws2_b) {
    vf2* ws = (vf2*)d_ws;
    ngp_gather_kernel<<<NB * NL / 256, 256, 0, stream>>>(x, tables, ws);
    ngp_transpose_kernel<<<NB / 256, 256, 0, stream>>>(ws, (vf4*)out);
  } else {
    ngp_fused_kernel<<<NB * NL / 256, 256, 0, stream>>>(x, tables, out);
  }
}